// Round 11
// baseline (419.669 us; speedup 1.0000x reference)
//
#include <hip/hip_runtime.h>
#include <hip/hip_bf16.h>

#define D_MODEL 1024
#define N_HEADS 16
#define D_HEAD  64
#define BATCH   4
#define SEQ     2048
#define LOG2E   1.44269504088896f

typedef __attribute__((ext_vector_type(8))) short short8;
typedef __attribute__((ext_vector_type(8))) unsigned short ushort8;
typedef __attribute__((ext_vector_type(4))) unsigned short ushort4v;
typedef __attribute__((ext_vector_type(4))) float f32x4;
typedef __attribute__((ext_vector_type(16))) float f32x16;
typedef unsigned int u32;

__device__ inline unsigned short f2bf(float f) {
  unsigned int u = __builtin_bit_cast(unsigned int, f);
  u += 0x7fffu + ((u >> 16) & 1u);
  return (unsigned short)(u >> 16);
}

__device__ inline float exp2_fast(float x) {
  return __builtin_amdgcn_exp2f(x);   // v_exp_f32: native 2^x
}

__device__ inline f32x4 mfma_bf16(short8 a, short8 b, f32x4 c) {
  return __builtin_amdgcn_mfma_f32_16x16x32_bf16(a, b, c, 0, 0, 0);
}

__device__ inline f32x16 mfma32(short8 a, short8 b, f32x16 c) {
  return __builtin_amdgcn_mfma_f32_32x32x16_bf16(a, b, c, 0, 0, 0);
}

// ---------------- fp32 -> bf16 conversion ----------------
__global__ void cvt_kernel(const float* __restrict__ src,
                           unsigned short* __restrict__ dst, int n) {
  int i = (blockIdx.x * 256 + threadIdx.x) * 8;
  if (i >= n) return;
  float4 a = *reinterpret_cast<const float4*>(src + i);
  float4 b = *reinterpret_cast<const float4*>(src + i + 4);
  ushort8 o;
  o[0] = f2bf(a.x); o[1] = f2bf(a.y); o[2] = f2bf(a.z); o[3] = f2bf(a.w);
  o[4] = f2bf(b.x); o[5] = f2bf(b.y); o[6] = f2bf(b.z); o[7] = f2bf(b.w);
  *reinterpret_cast<ushort8*>(dst + i) = o;
}

// ---------------- swizzled global->LDS staging (256 threads) --------------
template<int NBYTES>
__device__ inline void stage_swz(const unsigned short* g0, int g_stride_elems,
                                 unsigned short* lds0, int tid) {
#pragma unroll
  for (int it = 0; it < NBYTES / 4096; ++it) {
    int o = it * 4096 + tid * 16;
    int r = o >> 7;
    int cb = (o & 127) ^ ((r & 7) << 4);
    unsigned short* g = const_cast<unsigned short*>(g0) +
                        (size_t)r * g_stride_elems + (cb >> 1);
    unsigned short* l = lds0 + (o >> 1);
    __builtin_amdgcn_global_load_lds((__attribute__((address_space(1))) void*)g,
                                     (__attribute__((address_space(3))) void*)l,
                                     16, 0, 0);
  }
}

// ---------------- swizzled global->LDS staging (512 threads) --------------
template<int NBYTES>
__device__ inline void stage512(const unsigned short* g0, int g_stride_elems,
                                unsigned short* lds0, int tid) {
#pragma unroll
  for (int it = 0; it < NBYTES / 8192; ++it) {
    int o = it * 8192 + tid * 16;
    int r = o >> 7;
    int cb = (o & 127) ^ ((r & 7) << 4);
    unsigned short* g = const_cast<unsigned short*>(g0) +
                        (size_t)r * g_stride_elems + (cb >> 1);
    unsigned short* l = lds0 + (o >> 1);
    __builtin_amdgcn_global_load_lds((__attribute__((address_space(1))) void*)g,
                                     (__attribute__((address_space(3))) void*)l,
                                     16, 0, 0);
  }
}

// swizzled LDS fragment read (16B): row-stride fixed 128B
__device__ inline short8 frag_ld(const unsigned short* tile, int row, int col_el) {
  int cb = (col_el << 1) ^ ((row & 7) << 4);
  return *reinterpret_cast<const short8*>(
      reinterpret_cast<const char*>(tile) + row * 128 + cb);
}

// ---------------- QKV projection GEMM ----------------
// z=0 -> Q scaled by 0.125 (softmax scale), z=1 -> K, z=2 -> V^T
__launch_bounds__(256, 2)
__global__ void qkv_gemm(const unsigned short* __restrict__ xb,
                         const unsigned short* __restrict__ wb,
                         unsigned short* __restrict__ Qo,
                         unsigned short* __restrict__ Ko,
                         unsigned short* __restrict__ Vt) {
  __shared__ __align__(16) unsigned short As[128][64];
  __shared__ __align__(16) unsigned short Bs[128][64];
  const int z = blockIdx.z;
  const int m0 = blockIdx.y * 128;
  const int n0 = blockIdx.x * 128;
  const int tid = threadIdx.x;
  const int lane = tid & 63;
  const int wv = tid >> 6;
  const int wr = wv >> 1, wc = wv & 1;
  const int lrow = lane & 15;
  const int lk8 = (lane >> 4) << 3;
  const unsigned short* w = wb + (size_t)z * D_MODEL * D_MODEL;

  f32x4 acc[4][4];
  const f32x4 zero = {0.f, 0.f, 0.f, 0.f};
#pragma unroll
  for (int i = 0; i < 4; ++i)
#pragma unroll
    for (int j = 0; j < 4; ++j) acc[i][j] = zero;

  for (int k0 = 0; k0 < D_MODEL; k0 += 64) {
    __syncthreads();
    stage_swz<16384>(xb + (size_t)m0 * D_MODEL + k0, D_MODEL, &As[0][0], tid);
    stage_swz<16384>(w  + (size_t)n0 * D_MODEL + k0, D_MODEL, &Bs[0][0], tid);
    __syncthreads();
#pragma unroll
    for (int ks = 0; ks < 2; ++ks) {
      short8 af[4], bfr[4];
#pragma unroll
      for (int mi = 0; mi < 4; ++mi)
        af[mi] = frag_ld(&As[0][0], wr * 64 + mi * 16 + lrow, ks * 32 + lk8);
#pragma unroll
      for (int ni = 0; ni < 4; ++ni)
        bfr[ni] = frag_ld(&Bs[0][0], wc * 64 + ni * 16 + lrow, ks * 32 + lk8);
      if (z != 2) {
#pragma unroll
        for (int mi = 0; mi < 4; ++mi)
#pragma unroll
          for (int ni = 0; ni < 4; ++ni)
            acc[mi][ni] = mfma_bf16(af[mi], bfr[ni], acc[mi][ni]);
      } else {
#pragma unroll
        for (int ni = 0; ni < 4; ++ni)
#pragma unroll
          for (int mi = 0; mi < 4; ++mi)
            acc[ni][mi] = mfma_bf16(bfr[ni], af[mi], acc[ni][mi]);
      }
    }
  }

  const int lrr = (lane >> 4) << 2;
  if (z != 2) {
    unsigned short* dst = (z == 0) ? Qo : Ko;
    const float scale = (z == 0) ? 0.125f : 1.0f;
#pragma unroll
    for (int mi = 0; mi < 4; ++mi)
#pragma unroll
      for (int ni = 0; ni < 4; ++ni)
#pragma unroll
        for (int r = 0; r < 4; ++r) {
          int m = m0 + wr * 64 + mi * 16 + lrr + r;
          int e = n0 + wc * 64 + ni * 16 + lrow;
          int b = m >> 11, s = m & (SEQ - 1);
          int h = e >> 6, dh = e & 63;
          dst[((size_t)(b * N_HEADS + h) * SEQ + s) * D_HEAD + dh] =
              f2bf(acc[mi][ni][r] * scale);
        }
  } else {
#pragma unroll
    for (int ni = 0; ni < 4; ++ni)
#pragma unroll
      for (int mi = 0; mi < 4; ++mi)
#pragma unroll
        for (int r = 0; r < 4; ++r) {
          int e = n0 + wc * 64 + ni * 16 + lrr + r;
          int m = m0 + wr * 64 + mi * 16 + lrow;
          int b = m >> 11, s = m & (SEQ - 1);
          int h = e >> 6, dh = e & 63;
          Vt[((size_t)(b * N_HEADS + h) * D_HEAD + dh) * SEQ + s] =
              f2bf(acc[ni][mi][r]);
        }
  }
}

// ---------------- flash attention, 8-wave 256-q blocks, 32x32 MFMA --------
// Swapped QK^T via mfma_32x32x16(A=K, B=Q, C=bias): lane (q=lane&31, hi)
// holds S[k = kb*32 + (r&3)+8*(r>>2)+4*hi][q] (verified 32x32 C/D map) ->
// softmax is LANE-LOCAL except one __shfl_xor(32) for the hi-half merge.
// P goes through a small per-wave LDS buffer, stored by TRUE k (from the
// C/D map) and read back as b128 B-fragments (tau-consistent with V's A
// read -> robust to any consistent k-slot permutation). PV = mfma(A=V,B=P)
// keeps O's q lane-local (corr/inv need no shuffles).
__device__ __forceinline__ void astep(
    const unsigned short* Kt, const unsigned short* Vtile,
    unsigned short (*PsW)[72], const f32x4 (&bc)[2][4],
    f32x16 (&oa)[2], const short8 (&qb)[4],
    float& m_run, float& l_run, int lq, int hi) {
  // QK^T: S[k64][q32] in 2 f32x16 accs, bias as C-init
  f32x16 s[2];
#pragma unroll
  for (int kb = 0; kb < 2; ++kb)
#pragma unroll
    for (int rg = 0; rg < 4; ++rg)
#pragma unroll
      for (int c = 0; c < 4; ++c) s[kb][rg * 4 + c] = bc[kb][rg][c];

  __builtin_amdgcn_s_setprio(1);
#pragma unroll
  for (int kb = 0; kb < 2; ++kb)
#pragma unroll
    for (int dhs = 0; dhs < 4; ++dhs) {
      short8 kf = frag_ld(Kt, kb * 32 + lq, dhs * 16 + hi * 8);
      s[kb] = mfma32(kf, qb[dhs], s[kb]);
    }
  __builtin_amdgcn_s_setprio(0);

  // lane-local online softmax; one shuffle merges the hi-halves
  float pmax = s[0][0];
#pragma unroll
  for (int kb = 0; kb < 2; ++kb)
#pragma unroll
    for (int r = 0; r < 16; ++r) pmax = fmaxf(pmax, s[kb][r]);
  pmax = fmaxf(pmax, __shfl_xor(pmax, 32));

  if (!__all(pmax - m_run <= 7.6f)) {   // defer-max (7.6 raw ~ 11 log2)
    float mnew = fmaxf(m_run, pmax);
    float corr = exp2_fast((m_run - mnew) * LOG2E);
    l_run *= corr;
    m_run = mnew;
#pragma unroll
    for (int db = 0; db < 2; ++db)
#pragma unroll
      for (int r = 0; r < 16; ++r) oa[db][r] *= corr;
  }

  // exp + store P to LDS by true k: reg rg*4+c -> k = kb*32 + rg*8 + 4*hi + c
  const float mL = m_run * LOG2E;
  float rs = 0.f;
#pragma unroll
  for (int kb = 0; kb < 2; ++kb)
#pragma unroll
    for (int rg = 0; rg < 4; ++rg) {
      float p0 = exp2_fast(__builtin_fmaf(s[kb][rg * 4 + 0], LOG2E, -mL));
      float p1 = exp2_fast(__builtin_fmaf(s[kb][rg * 4 + 1], LOG2E, -mL));
      float p2 = exp2_fast(__builtin_fmaf(s[kb][rg * 4 + 2], LOG2E, -mL));
      float p3 = exp2_fast(__builtin_fmaf(s[kb][rg * 4 + 3], LOG2E, -mL));
      rs += (p0 + p1) + (p2 + p3);
      ushort4v pk;
      pk[0] = __builtin_bit_cast(unsigned short, __float2bfloat16(p0));
      pk[1] = __builtin_bit_cast(unsigned short, __float2bfloat16(p1));
      pk[2] = __builtin_bit_cast(unsigned short, __float2bfloat16(p2));
      pk[3] = __builtin_bit_cast(unsigned short, __float2bfloat16(p3));
      *reinterpret_cast<ushort4v*>(&PsW[lq][kb * 32 + rg * 8 + hi * 4]) = pk;
    }
  rs += __shfl_xor(rs, 32);
  l_run += rs;

  // PV: O[d64][q32] = V^T x P; A = V rows (LDS), B = P rows (LDS, b128)
  __builtin_amdgcn_s_setprio(1);
#pragma unroll
  for (int db = 0; db < 2; ++db)
#pragma unroll
    for (int ks = 0; ks < 4; ++ks) {
      short8 vf = frag_ld(Vtile, db * 32 + lq, ks * 16 + hi * 8);
      short8 pf = *reinterpret_cast<const short8*>(
          &PsW[lq][ks * 16 + hi * 8]);
      oa[db] = mfma32(vf, pf, oa[db]);
    }
  __builtin_amdgcn_s_setprio(0);
}

__launch_bounds__(512, 4)
__global__ void attn_kernel(const unsigned short* __restrict__ Q,
                            const unsigned short* __restrict__ K,
                            const unsigned short* __restrict__ Vt,
                            const float* __restrict__ bias,
                            unsigned short* __restrict__ ctx) {
  __shared__ __align__(16) unsigned short Ks[2][64][64];
  __shared__ __align__(16) unsigned short Vs[2][64][64];
  __shared__ __align__(16) unsigned short Ps[8][32][72];

  const int lid = blockIdx.x;                    // 512 blocks
  const int b = (lid >> 3) & 3;                  // batch-twins 8 ids apart
  const int h = ((lid & 7) << 1) | ((lid >> 5) & 1);  // h pinned to XCD slot
  const int q0 = ((lid >> 6) & 7) << 8;          // 8 q-blocks of 256

  const int tid = threadIdx.x;
  const int lane = tid & 63;
  const int w = tid >> 6;                        // wave 0..7
  const int lq = lane & 31;                      // q / m / n index
  const int hi = lane >> 5;
  const int qrow = q0 + w * 32 + lq;

  const size_t bh = (size_t)(b * N_HEADS + h);

  // Q fragments (B-operand) straight from global: dh = dhs*16 + 8*hi + j
  short8 qb[4];
  {
    const unsigned short* qp = Q + (bh * SEQ + qrow) * D_HEAD + hi * 8;
#pragma unroll
    for (int dhs = 0; dhs < 4; ++dhs)
      qb[dhs] = *reinterpret_cast<const short8*>(qp + dhs * 16);
  }

  // stage kv-tile 0; load bias tile 0
  stage512<8192>(K + bh * SEQ * D_HEAD, D_HEAD, &Ks[0][0][0], tid);
  stage512<8192>(Vt + bh * D_HEAD * SEQ, SEQ, &Vs[0][0][0], tid);

  const float* bq = bias + (size_t)h * SEQ * SEQ + (size_t)qrow * SEQ;
  f32x4 bA[2][4], bB[2][4];
#pragma unroll
  for (int kb = 0; kb < 2; ++kb)
#pragma unroll
    for (int rg = 0; rg < 4; ++rg)
      bA[kb][rg] = *reinterpret_cast<const f32x4*>(
          bq + kb * 32 + rg * 8 + hi * 4);

  float m_run = -1e30f, l_run = 0.f;
  f32x16 oa[2];
#pragma unroll
  for (int db = 0; db < 2; ++db)
#pragma unroll
    for (int r = 0; r < 16; ++r) oa[db][r] = 0.f;

  __syncthreads();   // tile 0 + bias ready (barrier drains vmcnt)

  for (int kt2 = 0; kt2 < 16; ++kt2) {
    {  // even step: kt = 2*kt2, buf 0, bias bA -> prefetch bB
      const int kt = 2 * kt2;
#pragma unroll
      for (int kb = 0; kb < 2; ++kb)
#pragma unroll
        for (int rg = 0; rg < 4; ++rg)
          bB[kb][rg] = *reinterpret_cast<const f32x4*>(
              bq + (kt + 1) * 64 + kb * 32 + rg * 8 + hi * 4);
      stage512<8192>(K + bh * SEQ * D_HEAD + (size_t)(kt + 1) * 64 * D_HEAD,
                     D_HEAD, &Ks[1][0][0], tid);
      stage512<8192>(Vt + bh * D_HEAD * SEQ + (kt + 1) * 64, SEQ,
                     &Vs[1][0][0], tid);
      astep(&Ks[0][0][0], &Vs[0][0][0], Ps[w], bA, oa, qb, m_run, l_run,
            lq, hi);
      __syncthreads();
    }
    {  // odd step: kt = 2*kt2+1, buf 1, bias bB -> prefetch bA
      const int kt = 2 * kt2 + 1;
      if (kt < 31) {
#pragma unroll
        for (int kb = 0; kb < 2; ++kb)
#pragma unroll
          for (int rg = 0; rg < 4; ++rg)
            bA[kb][rg] = *reinterpret_cast<const f32x4*>(
                bq + (kt + 1) * 64 + kb * 32 + rg * 8 + hi * 4);
        stage512<8192>(K + bh * SEQ * D_HEAD + (size_t)(kt + 1) * 64 * D_HEAD,
                       D_HEAD, &Ks[0][0][0], tid);
        stage512<8192>(Vt + bh * D_HEAD * SEQ + (kt + 1) * 64, SEQ,
                       &Vs[0][0][0], tid);
      }
      astep(&Ks[1][0][0], &Vs[1][0][0], Ps[w], bB, oa, qb, m_run, l_run,
            lq, hi);
      __syncthreads();
    }
  }

  // epilogue: normalize (lane-local) and store ctx [B,S,D_MODEL]
  float inv = 1.0f / l_run;
  unsigned short* cp = ctx + ((size_t)b * SEQ + qrow) * D_MODEL + h * 64;
#pragma unroll
  for (int db = 0; db < 2; ++db)
#pragma unroll
    for (int r = 0; r < 8; ++r) {
      float v0 = oa[db][2 * r] * inv;
      float v1 = oa[db][2 * r + 1] * inv;
      u32 pk_ = (u32)f2bf(v0) | ((u32)f2bf(v1) << 16);
      int d = db * 32 + ((2 * r) & 3) + 8 * ((2 * r) >> 2) + 4 * hi;
      *reinterpret_cast<u32*>(cp + d) = pk_;
    }
}

// ---------------- output projection GEMM (+bias, fp32 out) ----------------
__launch_bounds__(256, 2)
__global__ void out_gemm(const unsigned short* __restrict__ cb,
                         const unsigned short* __restrict__ wo,
                         const float* __restrict__ bo,
                         float* __restrict__ out) {
  __shared__ __align__(16) unsigned short As[128][64];
  __shared__ __align__(16) unsigned short Bs[128][64];
  const int m0 = blockIdx.y * 128;
  const int n0 = blockIdx.x * 128;
  const int tid = threadIdx.x;
  const int lane = tid & 63;
  const int wv = tid >> 6;
  const int wr = wv >> 1, wc = wv & 1;
  const int lrow = lane & 15;
  const int lk8 = (lane >> 4) << 3;

  f32x4 acc[4][4];
  const f32x4 zero = {0.f, 0.f, 0.f, 0.f};
#pragma unroll
  for (int i = 0; i < 4; ++i)
#pragma unroll
    for (int j = 0; j < 4; ++j) acc[i][j] = zero;

  for (int k0 = 0; k0 < D_MODEL; k0 += 64) {
    __syncthreads();
    stage_swz<16384>(cb + (size_t)m0 * D_MODEL + k0, D_MODEL, &As[0][0], tid);
    stage_swz<16384>(wo + (size_t)n0 * D_MODEL + k0, D_MODEL, &Bs[0][0], tid);
    __syncthreads();
#pragma unroll
    for (int ks = 0; ks < 2; ++ks) {
      short8 af[4], bfr[4];
#pragma unroll
      for (int mi = 0; mi < 4; ++mi)
        af[mi] = frag_ld(&As[0][0], wr * 64 + mi * 16 + lrow, ks * 32 + lk8);
#pragma unroll
      for (int ni = 0; ni < 4; ++ni)
        bfr[ni] = frag_ld(&Bs[0][0], wc * 64 + ni * 16 + lrow, ks * 32 + lk8);
#pragma unroll
      for (int mi = 0; mi < 4; ++mi)
#pragma unroll
        for (int ni = 0; ni < 4; ++ni)
          acc[mi][ni] = mfma_bf16(af[mi], bfr[ni], acc[mi][ni]);
    }
  }

  const int lrr = (lane >> 4) << 2;
#pragma unroll
  for (int mi = 0; mi < 4; ++mi)
#pragma unroll
    for (int ni = 0; ni < 4; ++ni)
#pragma unroll
      for (int r = 0; r < 4; ++r) {
        int m = m0 + wr * 64 + mi * 16 + lrr + r;
        int e = n0 + wc * 64 + ni * 16 + lrow;
        out[(size_t)m * D_MODEL + e] = acc[mi][ni][r] + bo[e];
      }
}

extern "C" void kernel_launch(void* const* d_in, const int* in_sizes, int n_in,
                              void* d_out, int out_size, void* d_ws, size_t ws_size,
                              hipStream_t stream) {
  const float* x    = (const float*)d_in[0];
  const float* bias = (const float*)d_in[1];
  const float* w_q  = (const float*)d_in[2];
  const float* w_k  = (const float*)d_in[3];
  const float* w_v  = (const float*)d_in[4];
  const float* w_o  = (const float*)d_in[5];
  const float* b_o  = (const float*)d_in[6];
  float* out = (float*)d_out;

  const size_t NX = (size_t)BATCH * SEQ * D_MODEL;       // 8388608
  const size_t NW = (size_t)D_MODEL * D_MODEL;           // 1048576

  unsigned short* xb    = (unsigned short*)d_ws;
  unsigned short* wqkvb = xb + NX;
  unsigned short* wob   = wqkvb + 3 * NW;
  unsigned short* Qb    = wob + NW;
  unsigned short* Kb    = Qb + NX;
  unsigned short* Vtb   = Kb + NX;
  unsigned short* ctxb  = Vtb + NX;

  cvt_kernel<<<(int)(NX / 2048), 256, 0, stream>>>(x, xb, (int)NX);
  cvt_kernel<<<(int)(NW / 2048), 256, 0, stream>>>(w_q, wqkvb, (int)NW);
  cvt_kernel<<<(int)(NW / 2048), 256, 0, stream>>>(w_k, wqkvb + NW, (int)NW);
  cvt_kernel<<<(int)(NW / 2048), 256, 0, stream>>>(w_v, wqkvb + 2 * NW, (int)NW);
  cvt_kernel<<<(int)(NW / 2048), 256, 0, stream>>>(w_o, wob, (int)NW);

  qkv_gemm<<<dim3(8, 64, 3), 256, 0, stream>>>(xb, wqkvb, Qb, Kb, Vtb);
  attn_kernel<<<512, 512, 0, stream>>>(Qb, Kb, Vtb, bias, ctxb);
  out_gemm<<<dim3(8, 64), 256, 0, stream>>>(ctxb, wob, b_o, out);
}